// Round 1
// baseline (1651.016 us; speedup 1.0000x reference)
//
#include <hip/hip_runtime.h>

#define NN 100000   // nodes
#define NE 1600000  // edges
#define CC 128      // channels
#define GG 50       // gaussians

typedef _Float16 half8 __attribute__((ext_vector_type(8)));
typedef float f32x4 __attribute__((ext_vector_type(4)));

static __device__ __forceinline__ f32x4 mfma16(half8 a, half8 b, f32x4 c) {
    return __builtin_amdgcn_mfma_f32_16x16x32_f16(a, b, c, 0, 0, 0);
}

// out[r][f] = sum_k in[r][k] * w[f][k] + bias[f]   (f16 MFMA, f32 accum)
// 64 rows per block, 256 threads (4 waves x 16 rows).
__global__ __launch_bounds__(256) void lin_kernel(const float* in, const float* w,
                                                  const float* bias, float* out, int nrows)
{
    __shared__ __align__(16) _Float16 a_lds[64][136];   // +8 pad: 2-way banks max
    __shared__ __align__(16) _Float16 bfrag[2048 * 8];  // [nb8][ks4][lane64][8]

    int tid = threadIdx.x;
    int rowBase = blockIdx.x * 64;

    // A tile 64x128 f32 -> f16 LDS (coalesced float4)
    for (int i = tid; i < 64 * 32; i += 256) {
        int r = i >> 5, c4 = i & 31;
        float4 v = {0.f, 0.f, 0.f, 0.f};
        if (rowBase + r < nrows)
            v = reinterpret_cast<const float4*>(in)[(size_t)(rowBase + r) * (CC / 4) + c4];
        a_lds[r][c4 * 4 + 0] = (_Float16)v.x;
        a_lds[r][c4 * 4 + 1] = (_Float16)v.y;
        a_lds[r][c4 * 4 + 2] = (_Float16)v.z;
        a_lds[r][c4 * 4 + 3] = (_Float16)v.w;
    }
    // B fragments in MFMA lane order: lane l holds B[k0..k0+7][f], f=nb*16+(l&15), k0=ks*32+8*(l>>4)
    for (int s = tid; s < 2048; s += 256) {
        int l = s & 63, ks = (s >> 6) & 3, nb = s >> 8;
        int f = nb * 16 + (l & 15);
        int k0 = ks * 32 + 8 * (l >> 4);
        const float* wp = w + f * CC + k0;
        half8 v;
        #pragma unroll
        for (int i = 0; i < 8; i++) v[i] = (_Float16)wp[i];
        *reinterpret_cast<half8*>(&bfrag[s * 8]) = v;
    }
    __syncthreads();

    int wid = tid >> 6, l = tid & 63;
    int lr = l & 15, lg = l >> 4;
    int wrow = wid * 16;

    half8 afr[4];
    #pragma unroll
    for (int ks = 0; ks < 4; ks++)
        afr[ks] = *reinterpret_cast<const half8*>(&a_lds[wrow + lr][ks * 32 + 8 * lg]);

    #pragma unroll
    for (int nb = 0; nb < 8; nb++) {
        f32x4 acc = {0.f, 0.f, 0.f, 0.f};
        #pragma unroll
        for (int ks = 0; ks < 4; ks++) {
            half8 bf = *reinterpret_cast<const half8*>(&bfrag[((nb * 4 + ks) * 64 + l) * 8]);
            acc = mfma16(afr[ks], bf, acc);
        }
        float bv = bias[nb * 16 + lr];
        #pragma unroll
        for (int j = 0; j < 4; j++) {
            int r = rowBase + wrow + lg * 4 + j;
            if (r < nrows) out[(size_t)r * CC + nb * 16 + lr] = acc[j] + bv;
        }
    }
}

// Fused per-edge: h = ssp(ea@fn1^T+b1); W = h@fn2^T+b2; atomicAdd(agg[row], x1[col]*W)
// 64 edges per block, 256 threads.
__global__ __launch_bounds__(256) void edge_kernel(
    const float* x1, const int* eidx, const float* ea,
    const float* fn1_w, const float* fn1_b,
    const float* fn2_w, const float* fn2_b, float* agg)
{
    __shared__ __align__(16) _Float16 ea_lds[64][72];   // g padded 50->64 (zeros), +8 banks
    __shared__ __align__(16) _Float16 h_lds[64][136];
    __shared__ __align__(16) _Float16 b2frag[2048 * 8]; // fn2 frags [nb8][ks4][lane64][8]
    __shared__ int rows_l[64];
    __shared__ int cols_l[64];

    int tid = threadIdx.x;
    size_t eBase = (size_t)blockIdx.x * 64;

    if (tid < 64) {
        rows_l[tid] = eidx[eBase + tid];
        cols_l[tid] = eidx[(size_t)NE + eBase + tid];
    }
    // edge_attr tile: 64*50 f32 contiguous = 1600 float2, coalesced
    {
        const float2* eap = reinterpret_cast<const float2*>(ea + eBase * GG);
        for (int i = tid; i < 1600; i += 256) {
            int e = i / 25, g2 = i - e * 25;
            float2 v = eap[i];
            ea_lds[e][g2 * 2 + 0] = (_Float16)v.x;
            ea_lds[e][g2 * 2 + 1] = (_Float16)v.y;
        }
        for (int i = tid; i < 64 * 14; i += 256) {   // zero K-pad g=50..63
            int e = i / 14, g = i - (i / 14) * 14 + 50;
            ea_lds[e][g] = (_Float16)0.f;
        }
    }
    // fn2 B frags -> LDS
    for (int s = tid; s < 2048; s += 256) {
        int l = s & 63, ks = (s >> 6) & 3, nb = s >> 8;
        int f = nb * 16 + (l & 15);
        int k0 = ks * 32 + 8 * (l >> 4);
        const float* wp = fn2_w + f * CC + k0;
        half8 v;
        #pragma unroll
        for (int i = 0; i < 8; i++) v[i] = (_Float16)wp[i];
        *reinterpret_cast<half8*>(&b2frag[s * 8]) = v;
    }

    int wid = tid >> 6, l = tid & 63;
    int lr = l & 15, lg = l >> 4;
    int wrow = wid * 16;

    // fn1 B frags -> registers (fn1_w is 25.6 KB, L1-resident; done once per block)
    half8 b1[8][2];
    #pragma unroll
    for (int nb = 0; nb < 8; nb++) {
        #pragma unroll
        for (int ks = 0; ks < 2; ks++) {
            int f = nb * 16 + lr;
            int k0 = ks * 32 + 8 * lg;
            #pragma unroll
            for (int i = 0; i < 8; i++) {
                int g = k0 + i;
                b1[nb][ks][i] = (g < GG) ? (_Float16)fn1_w[f * GG + g] : (_Float16)0.f;
            }
        }
    }
    __syncthreads();

    // ---- stage 1: h = shifted_softplus(ea @ fn1^T + fn1_b) ----
    half8 a1[2];
    #pragma unroll
    for (int ks = 0; ks < 2; ks++)
        a1[ks] = *reinterpret_cast<const half8*>(&ea_lds[wrow + lr][ks * 32 + 8 * lg]);

    #pragma unroll
    for (int nb = 0; nb < 8; nb++) {
        f32x4 acc = {0.f, 0.f, 0.f, 0.f};
        acc = mfma16(a1[0], b1[nb][0], acc);
        acc = mfma16(a1[1], b1[nb][1], acc);
        float bv = fn1_b[nb * 16 + lr];
        #pragma unroll
        for (int j = 0; j < 4; j++) {
            float z = acc[j] + bv;
            float t = __expf(-fabsf(z));                       // stable softplus
            float h = fmaxf(z, 0.f) + __logf(1.f + t) - 0.69314718055994531f;
            h_lds[wrow + lg * 4 + j][nb * 16 + lr] = (_Float16)h;
        }
    }
    __syncthreads();

    // ---- stage 2: W = h @ fn2^T + fn2_b ; msg = x1[col]*W ; scatter ----
    half8 a2[4];
    #pragma unroll
    for (int ks = 0; ks < 4; ks++)
        a2[ks] = *reinterpret_cast<const half8*>(&h_lds[wrow + lr][ks * 32 + 8 * lg]);

    #pragma unroll
    for (int nb = 0; nb < 8; nb++) {
        f32x4 acc = {0.f, 0.f, 0.f, 0.f};
        #pragma unroll
        for (int ks = 0; ks < 4; ks++) {
            half8 bf = *reinterpret_cast<const half8*>(&b2frag[((nb * 4 + ks) * 64 + l) * 8]);
            acc = mfma16(a2[ks], bf, acc);
        }
        float bv = fn2_b[nb * 16 + lr];
        int f = nb * 16 + lr;
        #pragma unroll
        for (int j = 0; j < 4; j++) {
            int eloc = wrow + lg * 4 + j;
            int col = cols_l[eloc];
            int row = rows_l[eloc];
            float wv = acc[j] + bv;
            float xv = ((unsigned)col < NN) ? x1[(size_t)col * CC + f] : 0.f;
            if ((unsigned)row < NN) atomicAdd(&agg[(size_t)row * CC + f], xv * wv);
        }
    }
}

extern "C" void kernel_launch(void* const* d_in, const int* in_sizes, int n_in,
                              void* d_out, int out_size, void* d_ws, size_t ws_size,
                              hipStream_t stream) {
    const float* x      = (const float*)d_in[0];
    const int*   eidx   = (const int*)d_in[1];
    const float* ea     = (const float*)d_in[2];
    const float* lin1_w = (const float*)d_in[3];
    const float* lin1_b = (const float*)d_in[4];
    const float* lin2_w = (const float*)d_in[5];
    const float* lin2_b = (const float*)d_in[6];
    const float* fn1_w  = (const float*)d_in[7];
    const float* fn1_b  = (const float*)d_in[8];
    const float* fn2_w  = (const float*)d_in[9];
    const float* fn2_b  = (const float*)d_in[10];

    float* out = (float*)d_out;
    float* x1  = (float*)d_ws;   // N*128 f32 = 51.2 MB scratch
    float* agg = out;            // accumulate into d_out, then lin2 in-place

    hipMemsetAsync(agg, 0, (size_t)NN * CC * sizeof(float), stream);

    lin_kernel<<<(NN + 63) / 64, 256, 0, stream>>>(x, lin1_w, lin1_b, x1, NN);
    edge_kernel<<<NE / 64, 256, 0, stream>>>(x1, eidx, ea, fn1_w, fn1_b, fn2_w, fn2_b, agg);
    lin_kernel<<<(NN + 63) / 64, 256, 0, stream>>>(agg, lin2_w, lin2_b, out, NN);
}

// Round 2
// 870.599 us; speedup vs baseline: 1.8964x; 1.8964x over previous
//
#include <hip/hip_runtime.h>

#define NN 100000   // nodes
#define NE 1600000  // edges
#define CC 128      // channels
#define GG 50       // gaussians
#define EPB 128     // edges per block

typedef _Float16 half8 __attribute__((ext_vector_type(8)));
typedef float f32x4 __attribute__((ext_vector_type(4)));

static __device__ __forceinline__ f32x4 mfma16(half8 a, half8 b, f32x4 c) {
    return __builtin_amdgcn_mfma_f32_16x16x32_f16(a, b, c, 0, 0, 0);
}

// ---------------------------------------------------------------------------
// Pack fn1 / fn2 weights into MFMA B-fragment order (f16) in ws.
// b1frag: [nb=8][ks=2][lane=64][8]  at ws_frag + 0       (16 KB)
// b2frag: [nb=8][ks=4][lane=64][8]  at ws_frag + 8192    (32 KB)
// lane l holds B[k0..k0+7][f], f = nb*16+(l&15), k0 = ks*32 + 8*(l>>4)
// ---------------------------------------------------------------------------
__global__ __launch_bounds__(256) void pack_frags(const float* fn1_w, const float* fn2_w,
                                                  _Float16* ws_frag)
{
    int tid = threadIdx.x;
    for (int s = tid; s < 1024; s += 256) {
        int l = s & 63, ks = (s >> 6) & 1, nb = s >> 7;
        int f = nb * 16 + (l & 15);
        int k0 = ks * 32 + 8 * (l >> 4);
        half8 v;
        #pragma unroll
        for (int i = 0; i < 8; i++) {
            int g = k0 + i;
            v[i] = (g < GG) ? (_Float16)fn1_w[f * GG + g] : (_Float16)0.f;
        }
        *reinterpret_cast<half8*>(&ws_frag[s * 8]) = v;
    }
    for (int s = tid; s < 2048; s += 256) {
        int l = s & 63, ks = (s >> 6) & 3, nb = s >> 8;
        int f = nb * 16 + (l & 15);
        int k0 = ks * 32 + 8 * (l >> 4);
        const float* wp = fn2_w + f * CC + k0;
        half8 v;
        #pragma unroll
        for (int i = 0; i < 8; i++) v[i] = (_Float16)wp[i];
        *reinterpret_cast<half8*>(&ws_frag[8192 + s * 8]) = v;
    }
}

// ---------------------------------------------------------------------------
// out[r][f] = sum_k in[r][k]*w[f][k] + bias[f]  (f16 MFMA, f32 accum)
// 64 rows/block, 256 threads.
// ---------------------------------------------------------------------------
__global__ __launch_bounds__(256) void lin_kernel(const float* in, const float* w,
                                                  const float* bias, float* out, int nrows)
{
    __shared__ __align__(16) _Float16 a_lds[64][136];
    __shared__ __align__(16) _Float16 bfrag[2048 * 8];

    int tid = threadIdx.x;
    int rowBase = blockIdx.x * 64;

    for (int i = tid; i < 64 * 32; i += 256) {
        int r = i >> 5, c4 = i & 31;
        float4 v = {0.f, 0.f, 0.f, 0.f};
        if (rowBase + r < nrows)
            v = reinterpret_cast<const float4*>(in)[(size_t)(rowBase + r) * (CC / 4) + c4];
        a_lds[r][c4 * 4 + 0] = (_Float16)v.x;
        a_lds[r][c4 * 4 + 1] = (_Float16)v.y;
        a_lds[r][c4 * 4 + 2] = (_Float16)v.z;
        a_lds[r][c4 * 4 + 3] = (_Float16)v.w;
    }
    for (int s = tid; s < 2048; s += 256) {
        int l = s & 63, ks = (s >> 6) & 3, nb = s >> 8;
        int f = nb * 16 + (l & 15);
        int k0 = ks * 32 + 8 * (l >> 4);
        const float* wp = w + f * CC + k0;
        half8 v;
        #pragma unroll
        for (int i = 0; i < 8; i++) v[i] = (_Float16)wp[i];
        *reinterpret_cast<half8*>(&bfrag[s * 8]) = v;
    }
    __syncthreads();

    int wid = tid >> 6, l = tid & 63;
    int lr = l & 15, lg = l >> 4;
    int wrow = wid * 16;

    half8 afr[4];
    #pragma unroll
    for (int ks = 0; ks < 4; ks++)
        afr[ks] = *reinterpret_cast<const half8*>(&a_lds[wrow + lr][ks * 32 + 8 * lg]);

    #pragma unroll
    for (int nb = 0; nb < 8; nb++) {
        f32x4 acc = {0.f, 0.f, 0.f, 0.f};
        #pragma unroll
        for (int ks = 0; ks < 4; ks++) {
            half8 bf = *reinterpret_cast<const half8*>(&bfrag[((nb * 4 + ks) * 64 + l) * 8]);
            acc = mfma16(afr[ks], bf, acc);
        }
        float bv = bias[nb * 16 + lr];
        #pragma unroll
        for (int j = 0; j < 4; j++) {
            int r = rowBase + wrow + lg * 4 + j;
            if (r < nrows) out[(size_t)r * CC + nb * 16 + lr] = acc[j] + bv;
        }
    }
}

// ---------------------------------------------------------------------------
// Fused edge kernel: 128 edges/block, 512 threads (8 waves x 16 edges).
// LDS: union{ea[128][64]f16 (16K) | h[128][128]f16 (32K)} + b2frag 32K + idx 1K
//   -> 66.5 KB, 2 blocks/CU, 16 waves/CU.
// XOR swizzle: byte ^= (e&7)<<4 spreads the 128B/256B row strides over banks.
// ---------------------------------------------------------------------------
__global__ __launch_bounds__(512, 4) void edge_kernel(
    const float* __restrict__ x1, const int* __restrict__ eidx,
    const float* __restrict__ ea, const _Float16* __restrict__ frag_ws,
    const float* __restrict__ fn1_b, const float* __restrict__ fn2_b,
    float* __restrict__ agg)
{
    __shared__ __align__(16) unsigned char u_lds[EPB * CC * 2];  // 32 KB (ea uses first 16K)
    __shared__ __align__(16) _Float16 b2_lds[2048 * 8];          // 32 KB
    __shared__ int rows_l[EPB];
    __shared__ int cols_l[EPB];

    int tid = threadIdx.x;
    size_t eBase = (size_t)blockIdx.x * EPB;

    if (tid < EPB) {
        rows_l[tid] = eidx[eBase + tid];
        cols_l[tid] = eidx[(size_t)NE + eBase + tid];
    }

    // fn2 fragments ws -> LDS (prepacked, coalesced b128)
    {
        const half8* b2g = reinterpret_cast<const half8*>(frag_ws + 8192);
        #pragma unroll
        for (int i = 0; i < 4; i++) {
            int s = tid + i * 512;
            *reinterpret_cast<half8*>(&b2_lds[s * 8]) = b2g[s];
        }
    }

    // edge_attr tile -> f16 LDS, swizzled rows of 64 (g 50..63 zero-padded)
    {
        const float2* eap = reinterpret_cast<const float2*>(ea + eBase * GG);
        for (int i = tid; i < EPB * 25; i += 512) {
            int e = i / 25, g2 = i - e * 25;
            float2 v = eap[i];
            int byte = e * 128 + ((g2 * 4) ^ ((e & 7) << 4));
            _Float16* p = reinterpret_cast<_Float16*>(u_lds + byte);
            p[0] = (_Float16)v.x;
            p[1] = (_Float16)v.y;
        }
        for (int i = tid; i < EPB * 14; i += 512) {
            int e = i / 14, g = (i - e * 14) + 50;
            int byte = e * 128 + ((g * 2) ^ ((e & 7) << 4));
            *reinterpret_cast<_Float16*>(u_lds + byte) = (_Float16)0.f;
        }
    }
    __syncthreads();

    int w = tid >> 6, l = tid & 63;
    int lr = l & 15, lg = l >> 4;
    int erow = w * 16;

    // stage-1 A fragments (each wave owns its 16 edges entirely -> regs)
    half8 a1[2];
    #pragma unroll
    for (int ks = 0; ks < 2; ks++) {
        int e = erow + lr;
        int byte = e * 128 + ((ks * 64 + lg * 16) ^ ((e & 7) << 4));
        a1[ks] = *reinterpret_cast<const half8*>(u_lds + byte);
    }
    // fn1 fragments from ws (L2-resident, coalesced b128)
    half8 b1[8][2];
    #pragma unroll
    for (int nb = 0; nb < 8; nb++)
        #pragma unroll
        for (int ks = 0; ks < 2; ks++)
            b1[nb][ks] = *reinterpret_cast<const half8*>(&frag_ws[((nb * 2 + ks) * 64 + l) * 8]);

    __syncthreads();  // all ea reads complete before h overwrites u_lds

    // ---- stage 1: h = shifted_softplus(ea @ fn1^T + b1) -> u_lds as [128][128] f16
    #pragma unroll
    for (int nb = 0; nb < 8; nb++) {
        f32x4 acc = {0.f, 0.f, 0.f, 0.f};
        acc = mfma16(a1[0], b1[nb][0], acc);
        acc = mfma16(a1[1], b1[nb][1], acc);
        float bv = fn1_b[nb * 16 + lr];
        int f = nb * 16 + lr;
        #pragma unroll
        for (int j = 0; j < 4; j++) {
            float z = acc[j] + bv;
            float t = __expf(-fabsf(z));
            float h = fmaxf(z, 0.f) + __logf(1.f + t) - 0.69314718055994531f;
            int e = erow + lg * 4 + j;
            int byte = e * 256 + ((f * 2) ^ ((e & 7) << 4));
            *reinterpret_cast<_Float16*>(u_lds + byte) = (_Float16)h;
        }
    }
    __syncthreads();

    // ---- stage 2: W = h @ fn2^T + b2 ; scatter x1[col]*W into agg[row]
    half8 a2[4];
    #pragma unroll
    for (int ks = 0; ks < 4; ks++) {
        int e = erow + lr;
        int byte = e * 256 + ((ks * 64 + lg * 16) ^ ((e & 7) << 4));
        a2[ks] = *reinterpret_cast<const half8*>(u_lds + byte);
    }

    int rr[4], cc4[4];
    #pragma unroll
    for (int j = 0; j < 4; j++) {
        int e = erow + lg * 4 + j;
        rr[j] = rows_l[e];
        cc4[j] = cols_l[e];
    }

    #pragma unroll
    for (int nb = 0; nb < 8; nb++) {
        f32x4 acc = {0.f, 0.f, 0.f, 0.f};
        #pragma unroll
        for (int ks = 0; ks < 4; ks++) {
            half8 bf = *reinterpret_cast<const half8*>(&b2_lds[((nb * 4 + ks) * 64 + l) * 8]);
            acc = mfma16(a2[ks], bf, acc);
        }
        float bv = fn2_b[nb * 16 + lr];
        int f = nb * 16 + lr;
        #pragma unroll
        for (int j = 0; j < 4; j++) {
            float wv = acc[j] + bv;
            float xv = x1[(size_t)cc4[j] * CC + f];
            atomicAdd(&agg[(size_t)rr[j] * CC + f], xv * wv);
        }
    }
}

extern "C" void kernel_launch(void* const* d_in, const int* in_sizes, int n_in,
                              void* d_out, int out_size, void* d_ws, size_t ws_size,
                              hipStream_t stream) {
    const float* x      = (const float*)d_in[0];
    const int*   eidx   = (const int*)d_in[1];
    const float* ea     = (const float*)d_in[2];
    const float* lin1_w = (const float*)d_in[3];
    const float* lin1_b = (const float*)d_in[4];
    const float* lin2_w = (const float*)d_in[5];
    const float* lin2_b = (const float*)d_in[6];
    const float* fn1_w  = (const float*)d_in[7];
    const float* fn1_b  = (const float*)d_in[8];
    const float* fn2_w  = (const float*)d_in[9];
    const float* fn2_b  = (const float*)d_in[10];

    float* out = (float*)d_out;
    _Float16* frag_ws = (_Float16*)d_ws;                     // 48 KB fragment pack
    float* x1  = (float*)((char*)d_ws + 65536);              // N*128 f32 = 51.2 MB
    float* agg = out;                                        // accumulate into d_out

    hipMemsetAsync(agg, 0, (size_t)NN * CC * sizeof(float), stream);

    pack_frags<<<1, 256, 0, stream>>>(fn1_w, fn2_w, frag_ws);
    lin_kernel<<<(NN + 63) / 64, 256, 0, stream>>>(x, lin1_w, lin1_b, x1, NN);
    edge_kernel<<<NE / EPB, 512, 0, stream>>>(x1, eidx, ea, frag_ws, fn1_b, fn2_b, agg);
    lin_kernel<<<(NN + 63) / 64, 256, 0, stream>>>(agg, lin2_w, lin2_b, out, NN);
}

// Round 3
// 787.971 us; speedup vs baseline: 2.0953x; 1.1049x over previous
//
#include <hip/hip_runtime.h>

#define NN 100000   // nodes
#define NE 1600000  // edges
#define CC 128      // channels
#define GG 50       // gaussians
#define EPB 128     // edges per block

typedef _Float16 half8 __attribute__((ext_vector_type(8)));
typedef float f32x4 __attribute__((ext_vector_type(4)));

static __device__ __forceinline__ f32x4 mfma16(half8 a, half8 b, f32x4 c) {
    return __builtin_amdgcn_mfma_f32_16x16x32_f16(a, b, c, 0, 0, 0);
}

// ---------------------------------------------------------------------------
// Pack fn1 / fn2 weights into MFMA B-fragment order (f16) in ws.
// b1frag: [nb=8][ks=2][lane=64][8]  at ws_frag + 0       (16 KB)
// b2frag: [nb=8][ks=4][lane=64][8]  at ws_frag + 8192*2B (32 KB)
// lane l holds B[k0..k0+7][f], f = nb*16+(l&15), k0 = ks*32 + 8*(l>>4)
// ---------------------------------------------------------------------------
__global__ __launch_bounds__(256) void pack_frags(const float* fn1_w, const float* fn2_w,
                                                  _Float16* ws_frag)
{
    int tid = threadIdx.x;
    for (int s = tid; s < 1024; s += 256) {
        int l = s & 63, ks = (s >> 6) & 1, nb = s >> 7;
        int f = nb * 16 + (l & 15);
        int k0 = ks * 32 + 8 * (l >> 4);
        half8 v;
        #pragma unroll
        for (int i = 0; i < 8; i++) {
            int g = k0 + i;
            v[i] = (g < GG) ? (_Float16)fn1_w[f * GG + g] : (_Float16)0.f;
        }
        *reinterpret_cast<half8*>(&ws_frag[s * 8]) = v;
    }
    for (int s = tid; s < 2048; s += 256) {
        int l = s & 63, ks = (s >> 6) & 3, nb = s >> 8;
        int f = nb * 16 + (l & 15);
        int k0 = ks * 32 + 8 * (l >> 4);
        const float* wp = fn2_w + f * CC + k0;
        half8 v;
        #pragma unroll
        for (int i = 0; i < 8; i++) v[i] = (_Float16)wp[i];
        *reinterpret_cast<half8*>(&ws_frag[8192 + s * 8]) = v;
    }
}

// ---------------------------------------------------------------------------
// out[r][f] = sum_k in[r][k]*w[f][k] + bias[f]  (f16 MFMA, f32 accum)
// 64 rows/block, 256 threads. OutT = float or _Float16.
// ---------------------------------------------------------------------------
template <typename OutT>
__global__ __launch_bounds__(256) void lin_kernel(const float* in, const float* w,
                                                  const float* bias, OutT* out, int nrows)
{
    __shared__ __align__(16) _Float16 a_lds[64][136];
    __shared__ __align__(16) _Float16 bfrag[2048 * 8];

    int tid = threadIdx.x;
    int rowBase = blockIdx.x * 64;

    for (int i = tid; i < 64 * 32; i += 256) {
        int r = i >> 5, c4 = i & 31;
        float4 v = {0.f, 0.f, 0.f, 0.f};
        if (rowBase + r < nrows)
            v = reinterpret_cast<const float4*>(in)[(size_t)(rowBase + r) * (CC / 4) + c4];
        a_lds[r][c4 * 4 + 0] = (_Float16)v.x;
        a_lds[r][c4 * 4 + 1] = (_Float16)v.y;
        a_lds[r][c4 * 4 + 2] = (_Float16)v.z;
        a_lds[r][c4 * 4 + 3] = (_Float16)v.w;
    }
    for (int s = tid; s < 2048; s += 256) {
        int l = s & 63, ks = (s >> 6) & 3, nb = s >> 8;
        int f = nb * 16 + (l & 15);
        int k0 = ks * 32 + 8 * (l >> 4);
        const float* wp = w + f * CC + k0;
        half8 v;
        #pragma unroll
        for (int i = 0; i < 8; i++) v[i] = (_Float16)wp[i];
        *reinterpret_cast<half8*>(&bfrag[s * 8]) = v;
    }
    __syncthreads();

    int wid = tid >> 6, l = tid & 63;
    int lr = l & 15, lg = l >> 4;
    int wrow = wid * 16;

    half8 afr[4];
    #pragma unroll
    for (int ks = 0; ks < 4; ks++)
        afr[ks] = *reinterpret_cast<const half8*>(&a_lds[wrow + lr][ks * 32 + 8 * lg]);

    #pragma unroll
    for (int nb = 0; nb < 8; nb++) {
        f32x4 acc = {0.f, 0.f, 0.f, 0.f};
        #pragma unroll
        for (int ks = 0; ks < 4; ks++) {
            half8 bf = *reinterpret_cast<const half8*>(&bfrag[((nb * 4 + ks) * 64 + l) * 8]);
            acc = mfma16(afr[ks], bf, acc);
        }
        float bv = bias[nb * 16 + lr];
        #pragma unroll
        for (int j = 0; j < 4; j++) {
            int r = rowBase + wrow + lg * 4 + j;
            if (r < nrows) out[(size_t)r * CC + nb * 16 + lr] = (OutT)(acc[j] + bv);
        }
    }
}

// ---------------------------------------------------------------------------
// Fused edge kernel: 128 edges/block, 512 threads (8 waves x 16 edges).
// LDS: union{ea[128][64]f16 (16K) | h[128][128]f16 (32K)} + idx 1K = 33.8 KB
//   -> 4 blocks/CU, 32 waves/CU (full occupancy).
// fn1/fn2 fragments read straight from ws (L2-resident, coalesced b128).
// XOR swizzle: byte ^= (e&7)<<4 spreads row strides over banks.
// ---------------------------------------------------------------------------
__global__ __launch_bounds__(512, 8) void edge_kernel(
    const _Float16* __restrict__ x1, const int* __restrict__ eidx,
    const float* __restrict__ ea, const _Float16* __restrict__ frag_ws,
    const float* __restrict__ fn1_b, const float* __restrict__ fn2_b,
    float* __restrict__ agg)
{
    __shared__ __align__(16) unsigned char u_lds[EPB * CC * 2];  // 32 KB
    __shared__ int rows_l[EPB];
    __shared__ int cols_l[EPB];

    int tid = threadIdx.x;
    size_t eBase = (size_t)blockIdx.x * EPB;

    if (tid < EPB) {
        rows_l[tid] = eidx[eBase + tid];
        cols_l[tid] = eidx[(size_t)NE + eBase + tid];
    }

    // edge_attr tile -> f16 LDS, swizzled rows of 64 (g 50..63 zero-padded)
    {
        const float2* eap = reinterpret_cast<const float2*>(ea + eBase * GG);
        for (int i = tid; i < EPB * 25; i += 512) {
            int e = i / 25, g2 = i - e * 25;
            float2 v = eap[i];
            int byte = e * 128 + ((g2 * 4) ^ ((e & 7) << 4));
            _Float16* p = reinterpret_cast<_Float16*>(u_lds + byte);
            p[0] = (_Float16)v.x;
            p[1] = (_Float16)v.y;
        }
        for (int i = tid; i < EPB * 14; i += 512) {
            int e = i / 14, g = (i - e * 14) + 50;
            int byte = e * 128 + ((g * 2) ^ ((e & 7) << 4));
            *reinterpret_cast<_Float16*>(u_lds + byte) = (_Float16)0.f;
        }
    }
    __syncthreads();

    int w = tid >> 6, l = tid & 63;
    int lr = l & 15, lg = l >> 4;
    int erow = w * 16;

    // stage-1 A fragments (each wave owns its 16 edges entirely -> regs)
    half8 a1[2];
    #pragma unroll
    for (int ks = 0; ks < 2; ks++) {
        int e = erow + lr;
        int byte = e * 128 + ((ks * 64 + lg * 16) ^ ((e & 7) << 4));
        a1[ks] = *reinterpret_cast<const half8*>(u_lds + byte);
    }

    __syncthreads();  // all ea reads complete before h overwrites u_lds

    // ---- stage 1: h = shifted_softplus(ea @ fn1^T + b1) -> u_lds [128][128] f16
    #pragma unroll
    for (int nb = 0; nb < 8; nb++) {
        half8 b10 = *reinterpret_cast<const half8*>(&frag_ws[((nb * 2 + 0) * 64 + l) * 8]);
        half8 b11 = *reinterpret_cast<const half8*>(&frag_ws[((nb * 2 + 1) * 64 + l) * 8]);
        f32x4 acc = {0.f, 0.f, 0.f, 0.f};
        acc = mfma16(a1[0], b10, acc);
        acc = mfma16(a1[1], b11, acc);
        float bv = fn1_b[nb * 16 + lr];
        int f = nb * 16 + lr;
        #pragma unroll
        for (int j = 0; j < 4; j++) {
            float z = acc[j] + bv;
            float t = __expf(-fabsf(z));
            float h = fmaxf(z, 0.f) + __logf(1.f + t) - 0.69314718055994531f;
            int e = erow + lg * 4 + j;
            int byte = e * 256 + ((f * 2) ^ ((e & 7) << 4));
            *reinterpret_cast<_Float16*>(u_lds + byte) = (_Float16)h;
        }
    }
    __syncthreads();

    // ---- stage 2: W = h @ fn2^T + b2 ; scatter x1[col]*W into agg[row]
    half8 a2[4];
    #pragma unroll
    for (int ks = 0; ks < 4; ks++) {
        int e = erow + lr;
        int byte = e * 256 + ((ks * 64 + lg * 16) ^ ((e & 7) << 4));
        a2[ks] = *reinterpret_cast<const half8*>(u_lds + byte);
    }

    int rr[4], cc4[4];
    #pragma unroll
    for (int j = 0; j < 4; j++) {
        int e = erow + lg * 4 + j;
        rr[j] = rows_l[e];
        cc4[j] = cols_l[e];
    }

    const half8* b2g = reinterpret_cast<const half8*>(frag_ws + 8192);
    #pragma unroll
    for (int nb = 0; nb < 8; nb++) {
        f32x4 acc = {0.f, 0.f, 0.f, 0.f};
        #pragma unroll
        for (int ks = 0; ks < 4; ks++) {
            half8 bf = b2g[(nb * 4 + ks) * 64 + l];
            acc = mfma16(a2[ks], bf, acc);
        }
        float bv = fn2_b[nb * 16 + lr];
        int f = nb * 16 + lr;
        #pragma unroll
        for (int j = 0; j < 4; j++) {
            float wv = acc[j] + bv;
            float xv = (float)x1[(size_t)cc4[j] * CC + f];
            atomicAdd(&agg[(size_t)rr[j] * CC + f], xv * wv);
        }
    }
}

extern "C" void kernel_launch(void* const* d_in, const int* in_sizes, int n_in,
                              void* d_out, int out_size, void* d_ws, size_t ws_size,
                              hipStream_t stream) {
    const float* x      = (const float*)d_in[0];
    const int*   eidx   = (const int*)d_in[1];
    const float* ea     = (const float*)d_in[2];
    const float* lin1_w = (const float*)d_in[3];
    const float* lin1_b = (const float*)d_in[4];
    const float* lin2_w = (const float*)d_in[5];
    const float* lin2_b = (const float*)d_in[6];
    const float* fn1_w  = (const float*)d_in[7];
    const float* fn1_b  = (const float*)d_in[8];
    const float* fn2_w  = (const float*)d_in[9];
    const float* fn2_b  = (const float*)d_in[10];

    float* out = (float*)d_out;
    _Float16* frag_ws = (_Float16*)d_ws;                 // 48 KB fragment pack
    _Float16* x1h = (_Float16*)((char*)d_ws + 65536);    // N*128 f16 = 25.6 MB
    float* agg = out;                                    // accumulate into d_out

    hipMemsetAsync(agg, 0, (size_t)NN * CC * sizeof(float), stream);

    pack_frags<<<1, 256, 0, stream>>>(fn1_w, fn2_w, frag_ws);
    lin_kernel<_Float16><<<(NN + 63) / 64, 256, 0, stream>>>(x, lin1_w, lin1_b, x1h, NN);
    edge_kernel<<<NE / EPB, 512, 0, stream>>>(x1h, eidx, ea, frag_ws, fn1_b, fn2_b, agg);
    lin_kernel<float><<<(NN + 63) / 64, 256, 0, stream>>>(agg, lin2_w, lin2_b, out, NN);
}

// Round 4
// 784.686 us; speedup vs baseline: 2.1040x; 1.0042x over previous
//
#include <hip/hip_runtime.h>

#define NN 100000   // nodes
#define NE 1600000  // edges
#define CC 128      // channels
#define GG 50       // gaussians
#define EPB 128     // edges per block
#define NSCB 98     // scan blocks: ceil(100000/1024)

typedef _Float16 half8 __attribute__((ext_vector_type(8)));
typedef float f32x4 __attribute__((ext_vector_type(4)));

static __device__ __forceinline__ f32x4 mfma16(half8 a, half8 b, f32x4 c) {
    return __builtin_amdgcn_mfma_f32_16x16x32_f16(a, b, c, 0, 0, 0);
}

// ---------------------------------------------------------------------------
// Pack fn1 / fn2 weights into MFMA B-fragment order (f16) in ws.
// b1frag: [nb=8][ks=2][lane=64][8] at 0 (16 KB); b2frag: [nb=8][ks=4][lane=64][8] at +8192 (32 KB)
// lane l holds B[k0..k0+7][f], f = nb*16+(l&15), k0 = ks*32 + 8*(l>>4)
// ---------------------------------------------------------------------------
__global__ __launch_bounds__(256) void pack_frags(const float* fn1_w, const float* fn2_w,
                                                  _Float16* ws_frag)
{
    int tid = threadIdx.x;
    for (int s = tid; s < 1024; s += 256) {
        int l = s & 63, ks = (s >> 6) & 1, nb = s >> 7;
        int f = nb * 16 + (l & 15);
        int k0 = ks * 32 + 8 * (l >> 4);
        half8 v;
        #pragma unroll
        for (int i = 0; i < 8; i++) {
            int g = k0 + i;
            v[i] = (g < GG) ? (_Float16)fn1_w[f * GG + g] : (_Float16)0.f;
        }
        *reinterpret_cast<half8*>(&ws_frag[s * 8]) = v;
    }
    for (int s = tid; s < 2048; s += 256) {
        int l = s & 63, ks = (s >> 6) & 3, nb = s >> 8;
        int f = nb * 16 + (l & 15);
        int k0 = ks * 32 + 8 * (l >> 4);
        const float* wp = fn2_w + f * CC + k0;
        half8 v;
        #pragma unroll
        for (int i = 0; i < 8; i++) v[i] = (_Float16)wp[i];
        *reinterpret_cast<half8*>(&ws_frag[8192 + s * 8]) = v;
    }
}

// ---------------------------------------------------------------------------
// out[r][f] = sum_k in[r][k]*w[f][k] + bias[f]  (f16 MFMA, f32 accum)
// ---------------------------------------------------------------------------
template <typename OutT>
__global__ __launch_bounds__(256) void lin_kernel(const float* in, const float* w,
                                                  const float* bias, OutT* out, int nrows)
{
    __shared__ __align__(16) _Float16 a_lds[64][136];
    __shared__ __align__(16) _Float16 bfrag[2048 * 8];

    int tid = threadIdx.x;
    int rowBase = blockIdx.x * 64;

    for (int i = tid; i < 64 * 32; i += 256) {
        int r = i >> 5, c4 = i & 31;
        float4 v = {0.f, 0.f, 0.f, 0.f};
        if (rowBase + r < nrows)
            v = reinterpret_cast<const float4*>(in)[(size_t)(rowBase + r) * (CC / 4) + c4];
        a_lds[r][c4 * 4 + 0] = (_Float16)v.x;
        a_lds[r][c4 * 4 + 1] = (_Float16)v.y;
        a_lds[r][c4 * 4 + 2] = (_Float16)v.z;
        a_lds[r][c4 * 4 + 3] = (_Float16)v.w;
    }
    for (int s = tid; s < 2048; s += 256) {
        int l = s & 63, ks = (s >> 6) & 3, nb = s >> 8;
        int f = nb * 16 + (l & 15);
        int k0 = ks * 32 + 8 * (l >> 4);
        const float* wp = w + f * CC + k0;
        half8 v;
        #pragma unroll
        for (int i = 0; i < 8; i++) v[i] = (_Float16)wp[i];
        *reinterpret_cast<half8*>(&bfrag[s * 8]) = v;
    }
    __syncthreads();

    int wid = tid >> 6, l = tid & 63;
    int lr = l & 15, lg = l >> 4;
    int wrow = wid * 16;

    half8 afr[4];
    #pragma unroll
    for (int ks = 0; ks < 4; ks++)
        afr[ks] = *reinterpret_cast<const half8*>(&a_lds[wrow + lr][ks * 32 + 8 * lg]);

    #pragma unroll
    for (int nb = 0; nb < 8; nb++) {
        f32x4 acc = {0.f, 0.f, 0.f, 0.f};
        #pragma unroll
        for (int ks = 0; ks < 4; ks++) {
            half8 bf = *reinterpret_cast<const half8*>(&bfrag[((nb * 4 + ks) * 64 + l) * 8]);
            acc = mfma16(afr[ks], bf, acc);
        }
        float bv = bias[nb * 16 + lr];
        #pragma unroll
        for (int j = 0; j < 4; j++) {
            int r = rowBase + wrow + lg * 4 + j;
            if (r < nrows) out[(size_t)r * CC + nb * 16 + lr] = (OutT)(acc[j] + bv);
        }
    }
}

// --------------------------- counting sort by row ---------------------------
__global__ __launch_bounds__(256) void hist_kernel(const int* row, int* cnt) {
    int e = blockIdx.x * 256 + threadIdx.x;
    if (e < NE) atomicAdd(&cnt[row[e]], 1);
}

__global__ __launch_bounds__(256) void scanA(const int* cnt, int* excl, int* bsum) {
    __shared__ int lds[256];
    int b = blockIdx.x, t = threadIdx.x;
    int base = b * 1024 + t * 4;
    int v[4];
    #pragma unroll
    for (int i = 0; i < 4; i++) v[i] = (base + i < NN) ? cnt[base + i] : 0;
    int s = v[0] + v[1] + v[2] + v[3];
    lds[t] = s;
    __syncthreads();
    for (int off = 1; off < 256; off <<= 1) {
        int x = (t >= off) ? lds[t - off] : 0;
        __syncthreads();
        lds[t] += x;
        __syncthreads();
    }
    int incl = lds[t];
    int run = incl - s;
    #pragma unroll
    for (int i = 0; i < 4; i++) {
        if (base + i < NN) excl[base + i] = run;
        run += v[i];
    }
    if (t == 255) bsum[b] = incl;
}

__global__ __launch_bounds__(128) void scanB(int* bsum) {
    __shared__ int lds[128];
    int t = threadIdx.x;
    int v = (t < NSCB) ? bsum[t] : 0;
    lds[t] = v;
    __syncthreads();
    for (int off = 1; off < 128; off <<= 1) {
        int x = (t >= off) ? lds[t - off] : 0;
        __syncthreads();
        lds[t] += x;
        __syncthreads();
    }
    if (t < NSCB) bsum[t] = lds[t] - v;  // exclusive
}

__global__ __launch_bounds__(256) void scanC(int* excl, const int* bsum) {
    int b = blockIdx.x, t = threadIdx.x;
    int off = bsum[b];
    int base = b * 1024 + t * 4;
    #pragma unroll
    for (int i = 0; i < 4; i++)
        if (base + i < NN) excl[base + i] += off;
}

__global__ __launch_bounds__(256) void build_perm(const int* row, int* cursor, int* perm) {
    int e = blockIdx.x * 256 + threadIdx.x;
    if (e < NE) {
        int r = row[e];
        int p = atomicAdd(&cursor[r], 1);
        perm[p] = e;
    }
}

// ---------------------------------------------------------------------------
// Sorted fused edge kernel: 128 sorted edges/block, 512 threads.
// Stages gathered ea rows, runs filter MFMAs, leaves msg[128][128] f16 in LDS,
// then segmented-reduces runs of equal row -> few atomics.
// LDS 33.5 KB -> 4 blocks/CU.
// ---------------------------------------------------------------------------
__global__ __launch_bounds__(512, 8) void edge_kernel_sorted(
    const _Float16* __restrict__ x1, const int* __restrict__ eidx,
    const float* __restrict__ ea, const _Float16* __restrict__ frag_ws,
    const float* __restrict__ fn1_b, const float* __restrict__ fn2_b,
    const int* __restrict__ perm, float* __restrict__ agg)
{
    __shared__ __align__(16) unsigned char u_lds[EPB * CC * 2];  // 32 KB
    __shared__ int pe_l[EPB];
    __shared__ int row_l[EPB];
    __shared__ int col_l[EPB];

    int tid = threadIdx.x;
    size_t eBase = (size_t)blockIdx.x * EPB;

    if (tid < EPB) pe_l[tid] = perm[eBase + tid];
    __syncthreads();

    if (tid < EPB) {
        int pe = pe_l[tid];
        row_l[tid] = eidx[pe];
        col_l[tid] = eidx[(size_t)NE + pe];
    }
    // gather ea rows (200B each) -> f16 LDS, swizzled; 4 threads/edge, float2 loads
    {
        int i = tid >> 2, p = tid & 3;
        int pe = pe_l[i];
        const float2* src = reinterpret_cast<const float2*>(ea + (size_t)pe * GG);
        int swz = (i & 7) << 4;
        #pragma unroll
        for (int it = 0; it < 7; it++) {
            int g2 = p + it * 4;
            if (g2 < 25) {
                float2 v = src[g2];
                int byte = i * 128 + ((g2 * 4) ^ swz);
                _Float16* q = reinterpret_cast<_Float16*>(u_lds + byte);
                q[0] = (_Float16)v.x;
                q[1] = (_Float16)v.y;
            }
        }
        #pragma unroll
        for (int it = 0; it < 2; it++) {   // zero-pad g = 50..63
            int g2 = 25 + p + it * 4;
            if (g2 < 32) {
                int byte = i * 128 + ((g2 * 4) ^ swz);
                _Float16* q = reinterpret_cast<_Float16*>(u_lds + byte);
                q[0] = (_Float16)0.f;
                q[1] = (_Float16)0.f;
            }
        }
    }
    __syncthreads();

    int w = tid >> 6, l = tid & 63;
    int lr = l & 15, lg = l >> 4;
    int erow = w * 16;

    // stage-1 A fragments (wave owns its 16 edges)
    half8 a1[2];
    #pragma unroll
    for (int ks = 0; ks < 2; ks++) {
        int e = erow + lr;
        int byte = e * 128 + ((ks * 64 + lg * 16) ^ ((e & 7) << 4));
        a1[ks] = *reinterpret_cast<const half8*>(u_lds + byte);
    }
    __syncthreads();  // all ea reads done before h overwrites u_lds

    // ---- stage 1: h = shifted_softplus(ea @ fn1^T + b1) -> u_lds [128][256B] f16
    #pragma unroll
    for (int nb = 0; nb < 8; nb++) {
        half8 b10 = *reinterpret_cast<const half8*>(&frag_ws[((nb * 2 + 0) * 64 + l) * 8]);
        half8 b11 = *reinterpret_cast<const half8*>(&frag_ws[((nb * 2 + 1) * 64 + l) * 8]);
        f32x4 acc = {0.f, 0.f, 0.f, 0.f};
        acc = mfma16(a1[0], b10, acc);
        acc = mfma16(a1[1], b11, acc);
        float bv = fn1_b[nb * 16 + lr];
        int f = nb * 16 + lr;
        #pragma unroll
        for (int j = 0; j < 4; j++) {
            float z = acc[j] + bv;
            float t = __expf(-fabsf(z));
            float h = fmaxf(z, 0.f) + __logf(1.f + t) - 0.69314718055994531f;
            int e = erow + lg * 4 + j;
            int byte = e * 256 + ((f * 2) ^ ((e & 7) << 4));
            *reinterpret_cast<_Float16*>(u_lds + byte) = (_Float16)h;
        }
    }
    __syncthreads();

    // ---- stage 2: W = h @ fn2^T + b2 ; msg = x1[col]*W -> back into u_lds (own rows)
    half8 a2[4];
    #pragma unroll
    for (int ks = 0; ks < 4; ks++) {
        int e = erow + lr;
        int byte = e * 256 + ((ks * 64 + lg * 16) ^ ((e & 7) << 4));
        a2[ks] = *reinterpret_cast<const half8*>(u_lds + byte);
    }

    int cc4[4];
    #pragma unroll
    for (int j = 0; j < 4; j++) cc4[j] = col_l[erow + lg * 4 + j];

    const half8* b2g = reinterpret_cast<const half8*>(frag_ws + 8192);
    #pragma unroll
    for (int nb = 0; nb < 8; nb++) {
        f32x4 acc = {0.f, 0.f, 0.f, 0.f};
        #pragma unroll
        for (int ks = 0; ks < 4; ks++) {
            half8 bf = b2g[(nb * 4 + ks) * 64 + l];
            acc = mfma16(a2[ks], bf, acc);
        }
        float bv = fn2_b[nb * 16 + lr];
        int f = nb * 16 + lr;
        #pragma unroll
        for (int j = 0; j < 4; j++) {
            int e = erow + lg * 4 + j;
            float wv = acc[j] + bv;
            float xv = (float)x1[(size_t)cc4[j] * CC + f];
            int byte = e * 256 + ((f * 2) ^ ((e & 7) << 4));
            *reinterpret_cast<_Float16*>(u_lds + byte) = (_Float16)(xv * wv);
        }
    }
    __syncthreads();

    // ---- segmented reduce: rows are sorted; collapse runs, few atomics ----
    {
        int f = tid & 127;
        int c0 = (tid >> 7) * 32;      // wave-uniform chunk
        float acc = 0.f;
        int cur = row_l[c0];
        for (int k = 0; k < 32; k++) {
            int e = c0 + k;
            int r = row_l[e];
            if (r != cur) {            // wave-uniform branch
                atomicAdd(&agg[(size_t)cur * CC + f], acc);
                acc = 0.f;
                cur = r;
            }
            int byte = e * 256 + ((f * 2) ^ ((e & 7) << 4));
            acc += (float)*reinterpret_cast<const _Float16*>(u_lds + byte);
        }
        atomicAdd(&agg[(size_t)cur * CC + f], acc);
    }
}

// ---------------- fallback (round-3) atomic edge kernel ----------------
__global__ __launch_bounds__(512, 8) void edge_kernel_atomic(
    const _Float16* __restrict__ x1, const int* __restrict__ eidx,
    const float* __restrict__ ea, const _Float16* __restrict__ frag_ws,
    const float* __restrict__ fn1_b, const float* __restrict__ fn2_b,
    float* __restrict__ agg)
{
    __shared__ __align__(16) unsigned char u_lds[EPB * CC * 2];
    __shared__ int rows_l[EPB];
    __shared__ int cols_l[EPB];

    int tid = threadIdx.x;
    size_t eBase = (size_t)blockIdx.x * EPB;

    if (tid < EPB) {
        rows_l[tid] = eidx[eBase + tid];
        cols_l[tid] = eidx[(size_t)NE + eBase + tid];
    }
    {
        const float2* eap = reinterpret_cast<const float2*>(ea + eBase * GG);
        for (int i = tid; i < EPB * 25; i += 512) {
            int e = i / 25, g2 = i - e * 25;
            float2 v = eap[i];
            int byte = e * 128 + ((g2 * 4) ^ ((e & 7) << 4));
            _Float16* p = reinterpret_cast<_Float16*>(u_lds + byte);
            p[0] = (_Float16)v.x;
            p[1] = (_Float16)v.y;
        }
        for (int i = tid; i < EPB * 14; i += 512) {
            int e = i / 14, g = (i - e * 14) + 50;
            int byte = e * 128 + ((g * 2) ^ ((e & 7) << 4));
            *reinterpret_cast<_Float16*>(u_lds + byte) = (_Float16)0.f;
        }
    }
    __syncthreads();

    int w = tid >> 6, l = tid & 63;
    int lr = l & 15, lg = l >> 4;
    int erow = w * 16;

    half8 a1[2];
    #pragma unroll
    for (int ks = 0; ks < 2; ks++) {
        int e = erow + lr;
        int byte = e * 128 + ((ks * 64 + lg * 16) ^ ((e & 7) << 4));
        a1[ks] = *reinterpret_cast<const half8*>(u_lds + byte);
    }
    __syncthreads();

    #pragma unroll
    for (int nb = 0; nb < 8; nb++) {
        half8 b10 = *reinterpret_cast<const half8*>(&frag_ws[((nb * 2 + 0) * 64 + l) * 8]);
        half8 b11 = *reinterpret_cast<const half8*>(&frag_ws[((nb * 2 + 1) * 64 + l) * 8]);
        f32x4 acc = {0.f, 0.f, 0.f, 0.f};
        acc = mfma16(a1[0], b10, acc);
        acc = mfma16(a1[1], b11, acc);
        float bv = fn1_b[nb * 16 + lr];
        int f = nb * 16 + lr;
        #pragma unroll
        for (int j = 0; j < 4; j++) {
            float z = acc[j] + bv;
            float t = __expf(-fabsf(z));
            float h = fmaxf(z, 0.f) + __logf(1.f + t) - 0.69314718055994531f;
            int e = erow + lg * 4 + j;
            int byte = e * 256 + ((f * 2) ^ ((e & 7) << 4));
            *reinterpret_cast<_Float16*>(u_lds + byte) = (_Float16)h;
        }
    }
    __syncthreads();

    half8 a2[4];
    #pragma unroll
    for (int ks = 0; ks < 4; ks++) {
        int e = erow + lr;
        int byte = e * 256 + ((ks * 64 + lg * 16) ^ ((e & 7) << 4));
        a2[ks] = *reinterpret_cast<const half8*>(u_lds + byte);
    }

    int rr[4], cc4[4];
    #pragma unroll
    for (int j = 0; j < 4; j++) {
        int e = erow + lg * 4 + j;
        rr[j] = rows_l[e];
        cc4[j] = cols_l[e];
    }

    const half8* b2g = reinterpret_cast<const half8*>(frag_ws + 8192);
    #pragma unroll
    for (int nb = 0; nb < 8; nb++) {
        f32x4 acc = {0.f, 0.f, 0.f, 0.f};
        #pragma unroll
        for (int ks = 0; ks < 4; ks++) {
            half8 bf = b2g[(nb * 4 + ks) * 64 + l];
            acc = mfma16(a2[ks], bf, acc);
        }
        float bv = fn2_b[nb * 16 + lr];
        int f = nb * 16 + lr;
        #pragma unroll
        for (int j = 0; j < 4; j++) {
            float wv = acc[j] + bv;
            float xv = (float)x1[(size_t)cc4[j] * CC + f];
            atomicAdd(&agg[(size_t)rr[j] * CC + f], xv * wv);
        }
    }
}

extern "C" void kernel_launch(void* const* d_in, const int* in_sizes, int n_in,
                              void* d_out, int out_size, void* d_ws, size_t ws_size,
                              hipStream_t stream) {
    const float* x      = (const float*)d_in[0];
    const int*   eidx   = (const int*)d_in[1];
    const float* ea     = (const float*)d_in[2];
    const float* lin1_w = (const float*)d_in[3];
    const float* lin1_b = (const float*)d_in[4];
    const float* lin2_w = (const float*)d_in[5];
    const float* lin2_b = (const float*)d_in[6];
    const float* fn1_w  = (const float*)d_in[7];
    const float* fn1_b  = (const float*)d_in[8];
    const float* fn2_w  = (const float*)d_in[9];
    const float* fn2_b  = (const float*)d_in[10];

    float* out = (float*)d_out;
    float* agg = out;

    // ws layout
    const size_t o_frag   = 0;                       // 64 KB
    const size_t o_x1h    = 65536;                   // 25.6 MB
    const size_t o_perm   = o_x1h + (size_t)NN * CC * 2;          // 6.4 MB
    const size_t o_rowptr = o_perm + (size_t)NE * 4;              // 400 KB
    const size_t o_bsum   = o_rowptr + (size_t)(NN + 1) * 4 + 60; // align-ish
    const size_t o_cnt    = o_bsum + 1024;
    const size_t req      = o_cnt + (size_t)NN * 4;

    _Float16* frag_ws = (_Float16*)((char*)d_ws + o_frag);
    _Float16* x1h     = (_Float16*)((char*)d_ws + o_x1h);

    hipMemsetAsync(agg, 0, (size_t)NN * CC * sizeof(float), stream);
    pack_frags<<<1, 256, 0, stream>>>(fn1_w, fn2_w, frag_ws);
    lin_kernel<_Float16><<<(NN + 63) / 64, 256, 0, stream>>>(x, lin1_w, lin1_b, x1h, NN);

    if (ws_size >= req) {
        int* perm   = (int*)((char*)d_ws + o_perm);
        int* rowptr = (int*)((char*)d_ws + o_rowptr);
        int* bsum   = (int*)((char*)d_ws + o_bsum);
        int* cnt    = (int*)((char*)d_ws + o_cnt);

        hipMemsetAsync(cnt, 0, (size_t)NN * 4, stream);
        hist_kernel<<<(NE + 255) / 256, 256, 0, stream>>>(eidx, cnt);
        scanA<<<NSCB, 256, 0, stream>>>(cnt, rowptr, bsum);
        scanB<<<1, 128, 0, stream>>>(bsum);
        scanC<<<NSCB, 256, 0, stream>>>(rowptr, bsum);
        build_perm<<<(NE + 255) / 256, 256, 0, stream>>>(eidx, rowptr, perm);

        edge_kernel_sorted<<<NE / EPB, 512, 0, stream>>>(x1h, eidx, ea, frag_ws,
                                                         fn1_b, fn2_b, perm, agg);
    } else {
        edge_kernel_atomic<<<NE / EPB, 512, 0, stream>>>(x1h, eidx, ea, frag_ws,
                                                         fn1_b, fn2_b, agg);
    }

    lin_kernel<float><<<(NN + 63) / 64, 256, 0, stream>>>(agg, lin2_w, lin2_b, out, NN);
}